// Round 21
// baseline (392.991 us; speedup 1.0000x reference)
//
#include <hip/hip_runtime.h>

typedef __attribute__((ext_vector_type(8))) short short8;
typedef __attribute__((ext_vector_type(4))) float f32x4;
typedef __attribute__((ext_vector_type(2))) unsigned u32x2;
typedef __attribute__((ext_vector_type(4))) unsigned u32x4;
typedef unsigned short u16;

#define MFMA16 __builtin_amdgcn_mfma_f32_16x16x32_bf16
#define PRIO1() __builtin_amdgcn_s_setprio(1)
#define PRIO0() __builtin_amdgcn_s_setprio(0)

__device__ __forceinline__ u16 f2bf(float f) {
  unsigned u = __builtin_bit_cast(unsigned, f);
  u += 0x7fffu + ((u >> 16) & 1u);  // RTNE (setup only)
  return (u16)(u >> 16);
}
// 4-op round-half-up pair pack (R13-proven; HW v_cvt_pk asm stays banned)
__device__ __forceinline__ unsigned cvtpk(float a, float b) {
  const unsigned ua = __builtin_bit_cast(unsigned, a) + 0x8000u;
  const unsigned ub = __builtin_bit_cast(unsigned, b) + 0x8000u;
  return (ua >> 16) | (ub & 0xffff0000u);
}

// ---------------------------------------------------------------------------
// Setup: bf16 weights (q pre-scaled by scale*log2e), scaled bias, and the
// bias+mask table in f32 C-FRAGMENT layout (phase-2 MFMA C-initializer):
//   bmf[w][h][tile=tkt*4+tqt][lane][i] = biasT[tk][tq] * log2e,
//   sentinel -30000 for tk>=49; 0 for padded tq.
// ws: qkvw@0 (98304B) projw@98304 (32768B) qkvbs@131072 (1536B)
//     bmf@133120 (4194304B f32)
// ---------------------------------------------------------------------------
__global__ void setup_misc(const float* __restrict__ qkv_w,
                           const float* __restrict__ qkv_b,
                           const float* __restrict__ proj_w,
                           const float* __restrict__ mask,
                           const float* __restrict__ rpb,
                           const int* __restrict__ rel_idx,
                           u16* __restrict__ qkvw, u16* __restrict__ projw,
                           float* __restrict__ qkvbs, float* __restrict__ bmf) {
  const int i = blockIdx.x * 256 + threadIdx.x;
  const float LOG2E = 1.44269504088896f;
  const float qsc = 0.17677669529663687f * LOG2E;  // 1/sqrt(32) * log2e
  if (i < 384 * 128) qkvw[i] = f2bf(qkv_w[i] * (i < 16384 ? qsc : 1.f));
  if (i < 128 * 128) projw[i] = f2bf(proj_w[i]);
  if (i < 384) qkvbs[i] = qkv_b[i] * (i < 128 ? qsc : 1.f);
  {  // i in [0,1048576): i4(2b) lane(6b) tile(4b) h(2b) w(6b)
    const int i4 = i & 3, lane = (i >> 2) & 63, tile = (i >> 8) & 15,
              h = (i >> 12) & 3, w = i >> 14;
    const int tkt = tile >> 2, tqt = tile & 3;
    const int g = lane >> 4, ln = lane & 15;
    const int tk = tkt * 16 + g * 4 + i4;
    const int tq = tqt * 16 + ln;
    float v = 0.f;
    if (tk >= 49)
      v = -30000.f;  // mask the reduction axis only
    else if (tq < 49)
      v = (rpb[rel_idx[tq * 49 + tk] * 4 + h] + mask[w * 2401 + tq * 49 + tk]) *
          LOG2E;
    bmf[i] = v;
  }
}

// ---------------------------------------------------------------------------
// Fused Swin block (R20 body + 2-window loop, R21).
// Grid 2048: each block processes 2 windows in a non-unrolled loop with ZERO
// loop-carried register state (R15 lesson: hoisted arrays spill at the
// 64-VGPR pin). Loop-top barrier guards smem reuse across windows.
// 1 block = 1 window per iteration, wave h owns head h.
// Phase 0: cooperative x->bf16 into 16KB LDS x-tile (R17: -21%).
// v in registers; PV A-frags via shuffles. Softmax: no max-subtraction,
// streaming exp2, 1/sum deferred. setprio(1) around MFMA clusters (T5, R19).
// Phase 4 output staged to LDS f32 image, cooperatively stored as full
// 512B-row f32x4 bursts (R20: WRITE 127->108.5 MB).
// LDS (32768 B), 16B-slot XOR swizzle keyed by row:
//  x    @ 0             : [64 row][256B] key=(row&7)<<4
//  q[h] @ h*8192        : [64 tok][64B]  key=(row&3)<<4
//  k[h] @ h*8192+4096   : [64 tok][64B]  key=(row&3)<<4
//  P[h] @ h*8192        : [64 tq][128B]  key=(row&7)<<4 (alias q||k)
//  tmp  @ 0             : [64 tok][256B] key=(row&7)<<4
//  ostg @ 0             : [64 row][512B f32] key=(row&7)<<4
// __launch_bounds__(256,4): VGPR cap 128 — real hw tier.
// ---------------------------------------------------------------------------
__global__ __launch_bounds__(256, 4) void swin_fused(
    const float* __restrict__ x, const float* __restrict__ qkvbs,
    const float* __restrict__ proj_b, const u16* __restrict__ qkvw,
    const u16* __restrict__ projw, const float* __restrict__ bmf,
    float* __restrict__ out) {
  __shared__ __align__(16) char smem[32768];
  const int tid = threadIdx.x;
  const int h = tid >> 6;  // wave = head
  const int lane = tid & 63;
  const int g = lane >> 4;
  const int ln = lane & 15;
  const unsigned key3 = (unsigned)((ln & 3) << 4);
  const unsigned key7 = (unsigned)((ln & 7) << 4);

#pragma unroll 1
  for (int wi = 0; wi < 2; ++wi) {
    const int b = blockIdx.x * 2 + wi;
    __syncthreads();  // B0: prior window's ostg reads done before x writes

    // ---------------- phase 0: cooperative x -> bf16 into LDS ------------
    {
      const int row = h * 16 + ln;  // wave h owns 16 rows; 4 lanes/row
      const unsigned kw = (unsigned)((row & 7) << 4);
      u32x4 w[4];
      if (row < 49) {
        const float* p = x + ((size_t)b * 49 + row) * 128 + g * 32;
#pragma unroll
        for (int s = 0; s < 4; ++s) {
          const f32x4 a0 = *(const f32x4*)(p + s * 8);
          const f32x4 a1 = *(const f32x4*)(p + s * 8 + 4);
          w[s] = u32x4{cvtpk(a0[0], a0[1]), cvtpk(a0[2], a0[3]),
                       cvtpk(a1[0], a1[1]), cvtpk(a1[2], a1[3])};
        }
      } else {
#pragma unroll
        for (int s = 0; s < 4; ++s) w[s] = u32x4{0u, 0u, 0u, 0u};
      }
#pragma unroll
      for (int s = 0; s < 4; ++s)
        *(u32x4*)(smem + row * 256 + (((unsigned)(g * 64 + s * 16)) ^ kw)) =
            w[s];
    }
    __syncthreads();  // Bc0: x-tile complete

    // ---------------- phase 1: aa frags from LDS --------------------------
    short8 aa[4][4];
#pragma unroll
    for (int mt = 0; mt < 4; ++mt)
#pragma unroll
      for (int kk = 0; kk < 4; ++kk)
        aa[mt][kk] = *(const short8*)(smem + (mt * 16 + ln) * 256 +
                                      (((unsigned)(kk * 64 + g * 16)) ^ key7));
    __syncthreads();  // Bc1: all aa reads done before q/k overlay x-tile

    // q^T, k^T: C[ch][tok] = mfma(W, x) -> LDS
#pragma unroll
    for (int qk = 0; qk < 2; ++qk)
#pragma unroll
      for (int Mt = 0; Mt < 2; ++Mt) {
        const int n = qk * 128 + h * 32 + Mt * 16 + ln;
        short8 wf[4];
#pragma unroll
        for (int kk = 0; kk < 4; ++kk)
          wf[kk] = *(const short8*)(qkvw + n * 128 + kk * 32 + g * 8);
        const f32x4 bq =
            *(const f32x4*)(qkvbs + qk * 128 + h * 32 + Mt * 16 + g * 4);
        f32x4 acc[4];
#pragma unroll
        for (int Nt = 0; Nt < 4; ++Nt) acc[Nt] = bq;
        PRIO1();
#pragma unroll
        for (int kk = 0; kk < 4; ++kk)
#pragma unroll
          for (int Nt = 0; Nt < 4; ++Nt)
            acc[Nt] = MFMA16(wf[kk], aa[Nt][kk], acc[Nt], 0, 0, 0);
        PRIO0();
#pragma unroll
        for (int Nt = 0; Nt < 4; ++Nt) {
          const int tok = Nt * 16 + ln;
          const u32x2 d2 = {cvtpk(acc[Nt][0], acc[Nt][1]),
                            cvtpk(acc[Nt][2], acc[Nt][3])};
          *(u32x2*)(smem + h * 8192 + qk * 4096 + tok * 64 +
                    (((unsigned)(Mt * 32 + g * 8)) ^ key3)) = d2;
        }
      }
    // v: C[tok][d] = mfma(x, W) -> packed bf16 dwords kept in REGISTERS.
    unsigned vdw[2][4][2];
#pragma unroll
    for (int dt = 0; dt < 2; ++dt) {
      const int n = 256 + h * 32 + dt * 16 + ln;
      short8 wf[4];
#pragma unroll
      for (int kk = 0; kk < 4; ++kk)
        wf[kk] = *(const short8*)(qkvw + n * 128 + kk * 32 + g * 8);
      const float bv = qkvbs[n];
      f32x4 acc[4];
#pragma unroll
      for (int mt = 0; mt < 4; ++mt) acc[mt] = f32x4{bv, bv, bv, bv};
      PRIO1();
#pragma unroll
      for (int kk = 0; kk < 4; ++kk)
#pragma unroll
        for (int mt = 0; mt < 4; ++mt)
          acc[mt] = MFMA16(aa[mt][kk], wf[kk], acc[mt], 0, 0, 0);
      PRIO0();
#pragma unroll
      for (int mt = 0; mt < 4; ++mt) {
        vdw[dt][mt][0] = cvtpk(acc[mt][0], acc[mt][1]);
        vdw[dt][mt][1] = cvtpk(acc[mt][2], acc[mt][3]);
      }
    }
    // no barrier: q/k/P traffic is wave-local until the tmp overlay

    // ------- phase 2: streaming S^T -> exp2 -> P~ (unnorm), su accum -----
    const float* bmb = bmf + ((size_t)((b & 63) * 4 + h)) * 4096;
    short8 kf[4], qf[4];
#pragma unroll
    for (int t = 0; t < 4; ++t) {
      const unsigned colb = ((unsigned)(g * 16)) ^ key3;
      kf[t] =
          *(const short8*)(smem + h * 8192 + 4096 + (t * 16 + ln) * 64 + colb);
      qf[t] = *(const short8*)(smem + h * 8192 + (t * 16 + ln) * 64 + colb);
    }
    float su[4] = {0.f, 0.f, 0.f, 0.f};
#pragma unroll
    for (int tkt = 0; tkt < 4; ++tkt)
#pragma unroll
      for (int tqt = 0; tqt < 4; ++tqt) {
        const f32x4 cin =
            *(const f32x4*)(bmb + ((tkt * 4 + tqt) * 64 + lane) * 4);
        PRIO1();
        f32x4 s4 = MFMA16(kf[tkt], qf[tqt], cin, 0, 0, 0);
        PRIO0();
        s4[0] = __builtin_amdgcn_exp2f(s4[0]);
        s4[1] = __builtin_amdgcn_exp2f(s4[1]);
        s4[2] = __builtin_amdgcn_exp2f(s4[2]);
        s4[3] = __builtin_amdgcn_exp2f(s4[3]);
        su[tqt] += (s4[0] + s4[1]) + (s4[2] + s4[3]);
        const u32x2 d2 = {cvtpk(s4[0], s4[1]), cvtpk(s4[2], s4[3])};
        *(u32x2*)(smem + h * 8192 + (tqt * 16 + ln) * 128 +
                  (((unsigned)(tkt * 32 + g * 8)) ^ key7)) = d2;  // P~
      }
    f32x4 rs;
#pragma unroll
    for (int tqt = 0; tqt < 4; ++tqt) {
      float s = su[tqt];
      s += __shfl_xor(s, 16);
      s += __shfl_xor(s, 32);
      s = fmaxf(s, 1e-37f);                // insurance (su provably > 0)
      rs[tqt] = __builtin_amdgcn_rcpf(s);  // 1/sum, applied at phase-3 out
    }

    // ---------------- phase 3: O^T = mfma(v, P~) * rs, v via shuffles ----
    const int src0 = (2 * (g & 1)) * 16 + ln;
    const int src1 = src0 + 16;
    short8 vf[2][2], pf[4][2];
#pragma unroll
    for (int Mt = 0; Mt < 2; ++Mt)
#pragma unroll
      for (int kk2 = 0; kk2 < 2; ++kk2) {
        u32x4 r;
#pragma unroll
        for (int w = 0; w < 4; ++w) {
          const int src = (w & 2) ? src1 : src0;
          const unsigned lo =
              (unsigned)__shfl((int)vdw[Mt][2 * kk2][w & 1], src);
          const unsigned hi =
              (unsigned)__shfl((int)vdw[Mt][2 * kk2 + 1][w & 1], src);
          r[w] = (g >= 2) ? hi : lo;
        }
        vf[Mt][kk2] = __builtin_bit_cast(short8, r);
      }
#pragma unroll
    for (int Nt = 0; Nt < 4; ++Nt)
#pragma unroll
      for (int kk2 = 0; kk2 < 2; ++kk2)
        pf[Nt][kk2] =
            *(const short8*)(smem + h * 8192 + (Nt * 16 + ln) * 128 +
                             (((unsigned)(kk2 * 64 + g * 16)) ^ key7));
    f32x4 o[2][4];
#pragma unroll
    for (int Mt = 0; Mt < 2; ++Mt)
#pragma unroll
      for (int Nt = 0; Nt < 4; ++Nt) o[Mt][Nt] = f32x4{0.f, 0.f, 0.f, 0.f};
    PRIO1();
#pragma unroll
    for (int kk2 = 0; kk2 < 2; ++kk2)
#pragma unroll
      for (int Mt = 0; Mt < 2; ++Mt)
#pragma unroll
        for (int Nt = 0; Nt < 4; ++Nt)
          o[Mt][Nt] = MFMA16(vf[Mt][kk2], pf[Nt][kk2], o[Mt][Nt], 0, 0, 0);
    PRIO0();
    __syncthreads();  // B3: q/k/P reads done before tmp overlays heads 0/1
#pragma unroll
    for (int Mt = 0; Mt < 2; ++Mt)
#pragma unroll
      for (int Nt = 0; Nt < 4; ++Nt) {
        const int tok = Nt * 16 + ln;
        const float r = rs[Nt];  // deferred softmax normalization
        const u32x2 d2 = {cvtpk(o[Mt][Nt][0] * r, o[Mt][Nt][1] * r),
                          cvtpk(o[Mt][Nt][2] * r, o[Mt][Nt][3] * r)};
        *(u32x2*)(smem + tok * 256 +
                  (((unsigned)((h * 32 + Mt * 16 + g * 4) * 2)) ^ key7)) = d2;
      }
    __syncthreads();  // B4: tmp complete

    // ------------- phase 4: out = mfma(tmp, projW) + proj_b --------------
    short8 at[4][4];
#pragma unroll
    for (int mt = 0; mt < 4; ++mt)
#pragma unroll
      for (int kk = 0; kk < 4; ++kk)
        at[mt][kk] = *(const short8*)(smem + (mt * 16 + ln) * 256 +
                                      (((unsigned)(kk * 64 + g * 16)) ^ key7));
    __syncthreads();  // B5: all at reads done before ostg overlays tmp/P
#pragma unroll
    for (int nti = 0; nti < 2; ++nti) {
      const int n = (h * 2 + nti) * 16 + ln;
      const float pb = proj_b[n];
      short8 pw[4];
#pragma unroll
      for (int kk = 0; kk < 4; ++kk)
        pw[kk] = *(const short8*)(projw + n * 128 + kk * 32 + g * 8);
      f32x4 acc[4];
#pragma unroll
      for (int mt = 0; mt < 4; ++mt) acc[mt] = f32x4{pb, pb, pb, pb};
      PRIO1();
#pragma unroll
      for (int kk = 0; kk < 4; ++kk)
#pragma unroll
        for (int mt = 0; mt < 4; ++mt)
          acc[mt] = MFMA16(at[mt][kk], pw[kk], acc[mt], 0, 0, 0);
      PRIO0();
      // stage to ostg f32 image: [row][col], 16B-slot swizzle key=(row&7)
#pragma unroll
      for (int mt = 0; mt < 4; ++mt)
#pragma unroll
        for (int i = 0; i < 4; ++i) {
          const int row = mt * 16 + g * 4 + i;
          if (row < 49)
            *(float*)(smem + row * 512 +
                      ((((unsigned)(n >> 2) ^ (unsigned)(row & 7)) << 4) +
                       ((n & 3) << 2))) = acc[mt][i];
        }
    }
    __syncthreads();  // B6: ostg complete

    // cooperative coalesced store: 49 rows x 32 f32x4 = 1568 vec4 stores
    float* ob = out + (size_t)b * (49 * 128);
#pragma unroll
    for (int it = 0; it < 7; ++it) {
      const int idx = it * 256 + tid;
      if (it < 6 || idx < 1568) {
        const int row = idx >> 5;  // 32 f32x4 per 512B row
        const int c4 = idx & 31;   // 16B slot within row
        const f32x4 v = *(const f32x4*)(smem + row * 512 +
                                        (((unsigned)(c4 ^ (row & 7))) << 4));
        *(f32x4*)(ob + (size_t)row * 128 + c4 * 4) = v;
      }
    }
  }
}

// ---------------------------------------------------------------------------
extern "C" void kernel_launch(void* const* d_in, const int* in_sizes, int n_in,
                              void* d_out, int out_size, void* d_ws,
                              size_t ws_size, hipStream_t stream) {
  const float* x = (const float*)d_in[0];
  const float* mask = (const float*)d_in[1];
  const float* qkv_w = (const float*)d_in[2];
  const float* qkv_b = (const float*)d_in[3];
  const float* proj_w = (const float*)d_in[4];
  const float* proj_b = (const float*)d_in[5];
  const float* rpb = (const float*)d_in[6];
  const int* rel = (const int*)d_in[7];

  u16* qkvw = (u16*)d_ws;
  u16* projw = (u16*)((char*)d_ws + 98304);
  float* qkvbs = (float*)((char*)d_ws + 131072);
  float* bmf = (float*)((char*)d_ws + 133120);  // 4 MB; total ws ~4.3 MB

  setup_misc<<<4096, 256, 0, stream>>>(qkv_w, qkv_b, proj_w, mask, rpb, rel,
                                       qkvw, projw, qkvbs, bmf);
  swin_fused<<<2048, 256, 0, stream>>>(x, qkvbs, proj_b, qkvw, projw, bmf,
                                       (float*)d_out);
}

// Round 22
// 105.737 us; speedup vs baseline: 3.7167x; 3.7167x over previous
//
#include <hip/hip_runtime.h>

typedef __attribute__((ext_vector_type(8))) short short8;
typedef __attribute__((ext_vector_type(4))) float f32x4;
typedef __attribute__((ext_vector_type(2))) unsigned u32x2;
typedef __attribute__((ext_vector_type(4))) unsigned u32x4;
typedef unsigned short u16;

#define MFMA16 __builtin_amdgcn_mfma_f32_16x16x32_bf16
#define PRIO1() __builtin_amdgcn_s_setprio(1)
#define PRIO0() __builtin_amdgcn_s_setprio(0)

__device__ __forceinline__ u16 f2bf(float f) {
  unsigned u = __builtin_bit_cast(unsigned, f);
  u += 0x7fffu + ((u >> 16) & 1u);  // RTNE (setup only)
  return (u16)(u >> 16);
}
// 4-op round-half-up pair pack (R13-proven; HW v_cvt_pk asm stays banned)
__device__ __forceinline__ unsigned cvtpk(float a, float b) {
  const unsigned ua = __builtin_bit_cast(unsigned, a) + 0x8000u;
  const unsigned ub = __builtin_bit_cast(unsigned, b) + 0x8000u;
  return (ua >> 16) | (ub & 0xffff0000u);
}

// ---------------------------------------------------------------------------
// Setup: bf16 weights (q pre-scaled by scale*log2e), scaled bias, and the
// bias+mask table in f32 C-FRAGMENT layout (phase-2 MFMA C-initializer):
//   bmf[w][h][tile=tkt*4+tqt][lane][i] = biasT[tk][tq] * log2e,
//   sentinel -30000 for tk>=49; 0 for padded tq.
// ws: qkvw@0 (98304B) projw@98304 (32768B) qkvbs@131072 (1536B)
//     bmf@133120 (4194304B f32)
// ---------------------------------------------------------------------------
__global__ void setup_misc(const float* __restrict__ qkv_w,
                           const float* __restrict__ qkv_b,
                           const float* __restrict__ proj_w,
                           const float* __restrict__ mask,
                           const float* __restrict__ rpb,
                           const int* __restrict__ rel_idx,
                           u16* __restrict__ qkvw, u16* __restrict__ projw,
                           float* __restrict__ qkvbs, float* __restrict__ bmf) {
  const int i = blockIdx.x * 256 + threadIdx.x;
  const float LOG2E = 1.44269504088896f;
  const float qsc = 0.17677669529663687f * LOG2E;  // 1/sqrt(32) * log2e
  if (i < 384 * 128) qkvw[i] = f2bf(qkv_w[i] * (i < 16384 ? qsc : 1.f));
  if (i < 128 * 128) projw[i] = f2bf(proj_w[i]);
  if (i < 384) qkvbs[i] = qkv_b[i] * (i < 128 ? qsc : 1.f);
  {  // i in [0,1048576): i4(2b) lane(6b) tile(4b) h(2b) w(6b)
    const int i4 = i & 3, lane = (i >> 2) & 63, tile = (i >> 8) & 15,
              h = (i >> 12) & 3, w = i >> 14;
    const int tkt = tile >> 2, tqt = tile & 3;
    const int g = lane >> 4, ln = lane & 15;
    const int tk = tkt * 16 + g * 4 + i4;
    const int tq = tqt * 16 + ln;
    float v = 0.f;
    if (tk >= 49)
      v = -30000.f;  // mask the reduction axis only
    else if (tq < 49)
      v = (rpb[rel_idx[tq * 49 + tk] * 4 + h] + mask[w * 2401 + tq * 49 + tk]) *
          LOG2E;
    bmf[i] = v;
  }
}

// ---------------------------------------------------------------------------
// Fused Swin block (R20 — proven best at 105.8us; R21's 2-window loop
// triggered the 64-VGPR regalloc spill storm even with zero loop-carried
// state. Body must stay straight-line, one window per block.)
// 1 block = 1 window, wave h owns head h.
// Phase 0: cooperative x->bf16 into 16KB LDS x-tile (R17: -21%).
// v in registers; PV A-frags via shuffles. Softmax: no max-subtraction,
// streaming exp2, 1/sum deferred. setprio(1) around MFMA clusters (T5, R19).
// Phase 4 output staged to LDS f32 image, cooperatively stored as full
// 512B-row f32x4 bursts (R20: WRITE 127->108.5 MB).
// LDS (32768 B), 16B-slot XOR swizzle keyed by row:
//  x    @ 0             : [64 row][256B] key=(row&7)<<4
//  q[h] @ h*8192        : [64 tok][64B]  key=(row&3)<<4
//  k[h] @ h*8192+4096   : [64 tok][64B]  key=(row&3)<<4
//  P[h] @ h*8192        : [64 tq][128B]  key=(row&7)<<4 (alias q||k)
//  tmp  @ 0             : [64 tok][256B] key=(row&7)<<4
//  ostg @ 0             : [64 row][512B f32] key=(row&7)<<4
// __launch_bounds__(256,4): VGPR cap 128 — real hw tier.
// ---------------------------------------------------------------------------
__global__ __launch_bounds__(256, 4) void swin_fused(
    const float* __restrict__ x, const float* __restrict__ qkvbs,
    const float* __restrict__ proj_b, const u16* __restrict__ qkvw,
    const u16* __restrict__ projw, const float* __restrict__ bmf,
    float* __restrict__ out) {
  __shared__ __align__(16) char smem[32768];
  const int b = blockIdx.x;
  const int tid = threadIdx.x;
  const int h = tid >> 6;  // wave = head
  const int lane = tid & 63;
  const int g = lane >> 4;
  const int ln = lane & 15;
  const unsigned key3 = (unsigned)((ln & 3) << 4);
  const unsigned key7 = (unsigned)((ln & 7) << 4);

  // ---------------- phase 0: cooperative x -> bf16 into LDS --------------
  {
    const int row = h * 16 + ln;  // wave h owns 16 rows; 4 lanes (g) per row
    const unsigned kw = (unsigned)((row & 7) << 4);
    u32x4 w[4];
    if (row < 49) {
      const float* p = x + ((size_t)b * 49 + row) * 128 + g * 32;
#pragma unroll
      for (int s = 0; s < 4; ++s) {
        const f32x4 a0 = *(const f32x4*)(p + s * 8);
        const f32x4 a1 = *(const f32x4*)(p + s * 8 + 4);
        w[s] = u32x4{cvtpk(a0[0], a0[1]), cvtpk(a0[2], a0[3]),
                     cvtpk(a1[0], a1[1]), cvtpk(a1[2], a1[3])};
      }
    } else {
#pragma unroll
      for (int s = 0; s < 4; ++s) w[s] = u32x4{0u, 0u, 0u, 0u};
    }
#pragma unroll
    for (int s = 0; s < 4; ++s)
      *(u32x4*)(smem + row * 256 + (((unsigned)(g * 64 + s * 16)) ^ kw)) = w[s];
  }
  __syncthreads();  // Bc0: x-tile complete

  // ---------------- phase 1: aa frags from LDS (A for v, B for q/k) ------
  short8 aa[4][4];
#pragma unroll
  for (int mt = 0; mt < 4; ++mt)
#pragma unroll
    for (int kk = 0; kk < 4; ++kk)
      aa[mt][kk] = *(const short8*)(smem + (mt * 16 + ln) * 256 +
                                    (((unsigned)(kk * 64 + g * 16)) ^ key7));
  __syncthreads();  // Bc1: all aa reads done before q/k overlay x-tile

  // q^T, k^T: C[ch][tok] = mfma(W, x) -> LDS
#pragma unroll
  for (int qk = 0; qk < 2; ++qk)
#pragma unroll
    for (int Mt = 0; Mt < 2; ++Mt) {
      const int n = qk * 128 + h * 32 + Mt * 16 + ln;
      short8 wf[4];
#pragma unroll
      for (int kk = 0; kk < 4; ++kk)
        wf[kk] = *(const short8*)(qkvw + n * 128 + kk * 32 + g * 8);
      const f32x4 bq = *(const f32x4*)(qkvbs + qk * 128 + h * 32 + Mt * 16 + g * 4);
      f32x4 acc[4];
#pragma unroll
      for (int Nt = 0; Nt < 4; ++Nt) acc[Nt] = bq;
      PRIO1();
#pragma unroll
      for (int kk = 0; kk < 4; ++kk)
#pragma unroll
        for (int Nt = 0; Nt < 4; ++Nt)
          acc[Nt] = MFMA16(wf[kk], aa[Nt][kk], acc[Nt], 0, 0, 0);
      PRIO0();
#pragma unroll
      for (int Nt = 0; Nt < 4; ++Nt) {
        const int tok = Nt * 16 + ln;
        const u32x2 d2 = {cvtpk(acc[Nt][0], acc[Nt][1]),
                          cvtpk(acc[Nt][2], acc[Nt][3])};
        *(u32x2*)(smem + h * 8192 + qk * 4096 + tok * 64 +
                  (((unsigned)(Mt * 32 + g * 8)) ^ key3)) = d2;
      }
    }
  // v: C[tok][d] = mfma(x, W) -> packed bf16 dwords kept in REGISTERS.
  unsigned vdw[2][4][2];
#pragma unroll
  for (int dt = 0; dt < 2; ++dt) {
    const int n = 256 + h * 32 + dt * 16 + ln;
    short8 wf[4];
#pragma unroll
    for (int kk = 0; kk < 4; ++kk)
      wf[kk] = *(const short8*)(qkvw + n * 128 + kk * 32 + g * 8);
    const float bv = qkvbs[n];
    f32x4 acc[4];
#pragma unroll
    for (int mt = 0; mt < 4; ++mt) acc[mt] = f32x4{bv, bv, bv, bv};
    PRIO1();
#pragma unroll
    for (int kk = 0; kk < 4; ++kk)
#pragma unroll
      for (int mt = 0; mt < 4; ++mt)
        acc[mt] = MFMA16(aa[mt][kk], wf[kk], acc[mt], 0, 0, 0);
    PRIO0();
#pragma unroll
    for (int mt = 0; mt < 4; ++mt) {
      vdw[dt][mt][0] = cvtpk(acc[mt][0], acc[mt][1]);
      vdw[dt][mt][1] = cvtpk(acc[mt][2], acc[mt][3]);
    }
  }
  // no barrier: q/k/P traffic is wave-local until the tmp overlay

  // ------- phase 2: streaming S^T -> exp2 -> P~ (unnorm), su accumulate --
  const float* bmb = bmf + ((size_t)((b & 63) * 4 + h)) * 4096;
  short8 kf[4], qf[4];
#pragma unroll
  for (int t = 0; t < 4; ++t) {
    const unsigned colb = ((unsigned)(g * 16)) ^ key3;
    kf[t] = *(const short8*)(smem + h * 8192 + 4096 + (t * 16 + ln) * 64 + colb);
    qf[t] = *(const short8*)(smem + h * 8192 + (t * 16 + ln) * 64 + colb);
  }
  float su[4] = {0.f, 0.f, 0.f, 0.f};
#pragma unroll
  for (int tkt = 0; tkt < 4; ++tkt)
#pragma unroll
    for (int tqt = 0; tqt < 4; ++tqt) {
      const f32x4 cin =
          *(const f32x4*)(bmb + ((tkt * 4 + tqt) * 64 + lane) * 4);
      PRIO1();
      f32x4 s4 = MFMA16(kf[tkt], qf[tqt], cin, 0, 0, 0);
      PRIO0();
      s4[0] = __builtin_amdgcn_exp2f(s4[0]);
      s4[1] = __builtin_amdgcn_exp2f(s4[1]);
      s4[2] = __builtin_amdgcn_exp2f(s4[2]);
      s4[3] = __builtin_amdgcn_exp2f(s4[3]);
      su[tqt] += (s4[0] + s4[1]) + (s4[2] + s4[3]);
      const u32x2 d2 = {cvtpk(s4[0], s4[1]), cvtpk(s4[2], s4[3])};
      *(u32x2*)(smem + h * 8192 + (tqt * 16 + ln) * 128 +
                (((unsigned)(tkt * 32 + g * 8)) ^ key7)) = d2;  // P~ (unnorm)
    }
  f32x4 rs;
#pragma unroll
  for (int tqt = 0; tqt < 4; ++tqt) {
    float s = su[tqt];
    s += __shfl_xor(s, 16);
    s += __shfl_xor(s, 32);
    s = fmaxf(s, 1e-37f);                // insurance (su provably > 0)
    rs[tqt] = __builtin_amdgcn_rcpf(s);  // 1/sum, applied at phase-3 output
  }

  // ---------------- phase 3: O^T = mfma(v, P~) * rs, v via shuffles ------
  const int src0 = (2 * (g & 1)) * 16 + ln;
  const int src1 = src0 + 16;
  short8 vf[2][2], pf[4][2];
#pragma unroll
  for (int Mt = 0; Mt < 2; ++Mt)
#pragma unroll
    for (int kk2 = 0; kk2 < 2; ++kk2) {
      u32x4 r;
#pragma unroll
      for (int w = 0; w < 4; ++w) {
        const int src = (w & 2) ? src1 : src0;
        const unsigned lo = (unsigned)__shfl((int)vdw[Mt][2 * kk2][w & 1], src);
        const unsigned hi = (unsigned)__shfl((int)vdw[Mt][2 * kk2 + 1][w & 1], src);
        r[w] = (g >= 2) ? hi : lo;
      }
      vf[Mt][kk2] = __builtin_bit_cast(short8, r);
    }
#pragma unroll
  for (int Nt = 0; Nt < 4; ++Nt)
#pragma unroll
    for (int kk2 = 0; kk2 < 2; ++kk2)
      pf[Nt][kk2] = *(const short8*)(smem + h * 8192 + (Nt * 16 + ln) * 128 +
                                     (((unsigned)(kk2 * 64 + g * 16)) ^ key7));
  f32x4 o[2][4];
#pragma unroll
  for (int Mt = 0; Mt < 2; ++Mt)
#pragma unroll
    for (int Nt = 0; Nt < 4; ++Nt) o[Mt][Nt] = f32x4{0.f, 0.f, 0.f, 0.f};
  PRIO1();
#pragma unroll
  for (int kk2 = 0; kk2 < 2; ++kk2)
#pragma unroll
    for (int Mt = 0; Mt < 2; ++Mt)
#pragma unroll
      for (int Nt = 0; Nt < 4; ++Nt)
        o[Mt][Nt] = MFMA16(vf[Mt][kk2], pf[Nt][kk2], o[Mt][Nt], 0, 0, 0);
  PRIO0();
  __syncthreads();  // B3: all q/k/P reads complete before tmp overlays heads 0/1
#pragma unroll
  for (int Mt = 0; Mt < 2; ++Mt)
#pragma unroll
    for (int Nt = 0; Nt < 4; ++Nt) {
      const int tok = Nt * 16 + ln;
      const float r = rs[Nt];  // deferred softmax normalization
      const u32x2 d2 = {cvtpk(o[Mt][Nt][0] * r, o[Mt][Nt][1] * r),
                        cvtpk(o[Mt][Nt][2] * r, o[Mt][Nt][3] * r)};
      *(u32x2*)(smem + tok * 256 +
                (((unsigned)((h * 32 + Mt * 16 + g * 4) * 2)) ^ key7)) = d2;
    }
  __syncthreads();  // B4: tmp complete

  // ---------------- phase 4: out = mfma(tmp, projW) + proj_b ----------------
  short8 at[4][4];
#pragma unroll
  for (int mt = 0; mt < 4; ++mt)
#pragma unroll
    for (int kk = 0; kk < 4; ++kk)
      at[mt][kk] = *(const short8*)(smem + (mt * 16 + ln) * 256 +
                                    (((unsigned)(kk * 64 + g * 16)) ^ key7));
  __syncthreads();  // B5: all at reads done before ostg overlays tmp/P
#pragma unroll
  for (int nti = 0; nti < 2; ++nti) {
    const int n = (h * 2 + nti) * 16 + ln;
    const float pb = proj_b[n];
    short8 pw[4];
#pragma unroll
    for (int kk = 0; kk < 4; ++kk)
      pw[kk] = *(const short8*)(projw + n * 128 + kk * 32 + g * 8);
    f32x4 acc[4];
#pragma unroll
    for (int mt = 0; mt < 4; ++mt) acc[mt] = f32x4{pb, pb, pb, pb};
    PRIO1();
#pragma unroll
    for (int kk = 0; kk < 4; ++kk)
#pragma unroll
      for (int mt = 0; mt < 4; ++mt)
        acc[mt] = MFMA16(at[mt][kk], pw[kk], acc[mt], 0, 0, 0);
    PRIO0();
    // stage to ostg f32 image: [row][col], 16B-slot swizzle key=(row&7)
#pragma unroll
    for (int mt = 0; mt < 4; ++mt)
#pragma unroll
      for (int i = 0; i < 4; ++i) {
        const int row = mt * 16 + g * 4 + i;
        if (row < 49)
          *(float*)(smem + row * 512 +
                    ((((unsigned)(n >> 2) ^ (unsigned)(row & 7)) << 4) +
                     ((n & 3) << 2))) = acc[mt][i];
      }
  }
  __syncthreads();  // B6: ostg complete

  // cooperative coalesced store: 49 rows x 32 f32x4 = 1568 vec4 stores
  float* ob = out + (size_t)b * (49 * 128);
#pragma unroll
  for (int it = 0; it < 7; ++it) {
    const int idx = it * 256 + tid;
    if (it < 6 || idx < 1568) {
      const int row = idx >> 5;       // 32 f32x4 per 512B row
      const int c4 = idx & 31;        // 16B slot within row
      const f32x4 v =
          *(const f32x4*)(smem + row * 512 +
                          (((unsigned)(c4 ^ (row & 7))) << 4));
      *(f32x4*)(ob + (size_t)row * 128 + c4 * 4) = v;
    }
  }
}

// ---------------------------------------------------------------------------
extern "C" void kernel_launch(void* const* d_in, const int* in_sizes, int n_in,
                              void* d_out, int out_size, void* d_ws,
                              size_t ws_size, hipStream_t stream) {
  const float* x = (const float*)d_in[0];
  const float* mask = (const float*)d_in[1];
  const float* qkv_w = (const float*)d_in[2];
  const float* qkv_b = (const float*)d_in[3];
  const float* proj_w = (const float*)d_in[4];
  const float* proj_b = (const float*)d_in[5];
  const float* rpb = (const float*)d_in[6];
  const int* rel = (const int*)d_in[7];

  u16* qkvw = (u16*)d_ws;
  u16* projw = (u16*)((char*)d_ws + 98304);
  float* qkvbs = (float*)((char*)d_ws + 131072);
  float* bmf = (float*)((char*)d_ws + 133120);  // 4 MB; total ws ~4.3 MB

  setup_misc<<<4096, 256, 0, stream>>>(qkv_w, qkv_b, proj_w, mask, rpb, rel,
                                       qkvw, projw, qkvbs, bmf);
  swin_fused<<<4096, 256, 0, stream>>>(x, qkvbs, proj_b, qkvw, projw, bmf,
                                       (float*)d_out);
}